// Round 6
// baseline (3499.124 us; speedup 1.0000x reference)
//
#include <hip/hip_runtime.h>
#include <cstdint>
#include <cstddef>

#define E_   8
#define H_   2048
#define F_   5632
#define N_   8192
#define CAP_ 2560
#define CC_  64
#define BB_  4

typedef __attribute__((ext_vector_type(8))) short s16x8;
typedef __attribute__((ext_vector_type(4))) float f32x4;

// ---------------- device scratch (fully re-written every call) ----------------
__device__ __align__(16) unsigned short g_w1t[(size_t)E_ * F_ * H_];   // [E][F][H] bf16 (B^T for GEMM1)
__device__ __align__(16) unsigned short g_w3t[(size_t)E_ * F_ * H_];   // [E][F][H] bf16
__device__ __align__(16) unsigned short g_w2t[(size_t)E_ * H_ * F_];   // [E][H][F] bf16 (B^T for GEMM2)
__device__ __align__(16) unsigned short g_A  [(size_t)E_ * CAP_ * H_]; // gated token buffers, bf16
__device__ __align__(16) unsigned short g_S1 [(size_t)E_ * CAP_ * F_]; // h = silu(A@w1)*(A@w3), bf16
__device__ __align__(16) float          g_eout[(size_t)E_ * CAP_ * H_];
__device__ int   g_slot_token[E_ * CAP_];
__device__ float g_slot_gate [E_ * CAP_];
__device__ int   g_tope  [2 * N_];   // k-major: [k][n]
__device__ float g_gatew [2 * N_];
__device__ int   g_slotof[2 * N_];   // slot per (k,n), -1 if dropped
__device__ int   g_cnt_all [E_];
__device__ int   g_cnt_used[E_];
__device__ float g_me[E_];
__device__ float g_ctxlog[BB_ * E_];

// ---------------- helpers ----------------
static __device__ __forceinline__ unsigned short f2bfu(float f) {
  unsigned int b = __builtin_bit_cast(unsigned int, f);
  unsigned int r = b + 0x7FFFu + ((b >> 16) & 1u);   // RTNE
  return (unsigned short)(r >> 16);
}
static __device__ __forceinline__ float bfu2f(unsigned short u) {
  unsigned int b = ((unsigned int)u) << 16;
  return __builtin_bit_cast(float, b);
}
static __device__ __forceinline__ void gload16(const void* g, void* l) {
  typedef __attribute__((address_space(1))) unsigned int gu32;
  typedef __attribute__((address_space(3))) unsigned int lu32;
  __builtin_amdgcn_global_load_lds((gu32*)((void*)g), (lu32*)l, 16, 0, 0);
}

// ---------------- weight convert + transpose: [E][R][C] f32 -> [E][C][R] bf16 ----------------
template <int SEL>  // 0: w1->g_w1t, 1: w3->g_w3t, 2: w2->g_w2t
__global__ __launch_bounds__(256) void k_convT(const float* __restrict__ in) {
  constexpr int R = (SEL == 2) ? F_ : H_;
  constexpr int C = (SEL == 2) ? H_ : F_;
  unsigned short* outp = (SEL == 0) ? g_w1t : (SEL == 1) ? g_w3t : g_w2t;
  __shared__ float tile[64][65];
  const int e  = blockIdx.z;
  const size_t ibase = (size_t)e * R * C;
  const int r0 = blockIdx.y * 64, c0 = blockIdx.x * 64;
  const int t  = threadIdx.x;
#pragma unroll
  for (int i = 0; i < 4; ++i) {
    int idx = i * 256 + t;            // [0,1024)
    int r = idx >> 4;                 // [0,64)
    int c = (idx & 15) * 4;           // [0,64)
    float4 v = *(const float4*)(in + ibase + (size_t)(r0 + r) * C + (c0 + c));
    tile[r][c] = v.x; tile[r][c + 1] = v.y; tile[r][c + 2] = v.z; tile[r][c + 3] = v.w;
  }
  __syncthreads();
#pragma unroll
  for (int i = 0; i < 4; ++i) {
    int idx = i * 1024 + t * 4;       // [0,4096)
    int cr = idx >> 6, rc = idx & 63; // rc multiple of 4
    ushort4 w;
    w.x = f2bfu(tile[rc][cr]);
    w.y = f2bfu(tile[rc + 1][cr]);
    w.z = f2bfu(tile[rc + 2][cr]);
    w.w = f2bfu(tile[rc + 3][cr]);
    *(ushort4*)(outp + ibase + (size_t)(c0 + cr) * R + (r0 + rc)) = w;
  }
}

// ---------------- context logits: tanh(ph @ Wctx) @ Wctx2 ----------------
__global__ __launch_bounds__(256) void k_ctx(const float* __restrict__ ph,
                                             const float* __restrict__ Wctx,
                                             const float* __restrict__ Wctx2) {
  __shared__ float ctx[BB_][CC_];
  const int t = threadIdx.x;
  const int b = t >> 6, c = t & 63;
  float s = 0.f;
#pragma unroll 8
  for (int h = 0; h < H_; ++h) s += ph[b * H_ + h] * Wctx[h * CC_ + c];
  ctx[b][c] = tanhf(s);
  __syncthreads();
  if (t < BB_ * E_) {
    int bb = t >> 3, e = t & 7;
    float s2 = 0.f;
#pragma unroll
    for (int cc = 0; cc < CC_; ++cc) s2 += ctx[bb][cc] * Wctx2[cc * E_ + e];
    g_ctxlog[bb * E_ + e] = s2;
  }
  if (t < E_) g_me[t] = 0.f;
}

// ---------------- router: rmsnorm -> logits -> softmax -> top2 ----------------
__global__ __launch_bounds__(256) void k_router(const float* __restrict__ x,
                                                const float* __restrict__ rmsw,
                                                const float* __restrict__ Wg) {
  __shared__ float sme[E_];
  const int t = threadIdx.x;
  if (t < E_) sme[t] = 0.f;
  __syncthreads();
  const int wave = t >> 6, lane = t & 63;
  const int n = blockIdx.x * 4 + wave;
  const float* xr = x + (size_t)n * H_;
  float xv[32];
  float ss = 0.f;
#pragma unroll
  for (int i = 0; i < 8; ++i) {
    float4 v = *(const float4*)(xr + i * 256 + lane * 4);
    xv[i*4+0] = v.x; xv[i*4+1] = v.y; xv[i*4+2] = v.z; xv[i*4+3] = v.w;
    ss += v.x*v.x + v.y*v.y + v.z*v.z + v.w*v.w;
  }
#pragma unroll
  for (int off = 32; off; off >>= 1) ss += __shfl_xor(ss, off);
  const float rn = rsqrtf(ss * (1.f / H_) + 1e-6f);
  float acc[8] = {0,0,0,0,0,0,0,0};
#pragma unroll
  for (int i = 0; i < 8; ++i) {
    float4 rw = *(const float4*)(rmsw + i * 256 + lane * 4);
    float rwv[4] = {rw.x, rw.y, rw.z, rw.w};
#pragma unroll
    for (int j = 0; j < 4; ++j) {
      int h = i * 256 + lane * 4 + j;
      float xw = xv[i*4+j] * rwv[j];
      float4 g0 = *(const float4*)(Wg + (size_t)h * E_);
      float4 g1 = *(const float4*)(Wg + (size_t)h * E_ + 4);
      acc[0] += xw * g0.x; acc[1] += xw * g0.y; acc[2] += xw * g0.z; acc[3] += xw * g0.w;
      acc[4] += xw * g1.x; acc[5] += xw * g1.y; acc[6] += xw * g1.z; acc[7] += xw * g1.w;
    }
  }
#pragma unroll
  for (int e = 0; e < 8; ++e) {
#pragma unroll
    for (int off = 32; off; off >>= 1) acc[e] += __shfl_xor(acc[e], off);
  }
  const int b = n >> 11;
  float lg[8], p[8];
  float mx = -1e30f;
#pragma unroll
  for (int e = 0; e < 8; ++e) { lg[e] = rn * acc[e] + g_ctxlog[b * E_ + e]; mx = fmaxf(mx, lg[e]); }
  float sum = 0.f;
#pragma unroll
  for (int e = 0; e < 8; ++e) { p[e] = expf(lg[e] - mx); sum += p[e]; }
  const float inv = 1.f / sum;
#pragma unroll
  for (int e = 0; e < 8; ++e) p[e] *= inv;
  // top-2, ties -> lower index (matches lax.top_k stability)
  int i0 = 0; float v0 = p[0];
#pragma unroll
  for (int e = 1; e < 8; ++e) if (p[e] > v0) { v0 = p[e]; i0 = e; }
  int i1 = 0; float v1 = -1.f;
#pragma unroll
  for (int e = 0; e < 8; ++e) if (e != i0 && p[e] > v1) { v1 = p[e]; i1 = e; }
  const float gs = 1.f / (v0 + v1);
  if (lane == 0) {
    g_tope[n] = i0;        g_tope[N_ + n] = i1;
    g_gatew[n] = v0 * gs;  g_gatew[N_ + n] = v1 * gs;
#pragma unroll
    for (int e = 0; e < 8; ++e) atomicAdd(&sme[e], p[e]);
  }
  __syncthreads();
  if (t < E_) atomicAdd(&g_me[t], sme[t]);
}

// ---------------- routing scan: k-major cumulative positions (exact JAX order) ----------------
__global__ __launch_bounds__(256) void k_scan() {
  __shared__ int hist[256][8];
  const int t = threadIdx.x;
  for (int i = t; i < E_ * CAP_; i += 256) g_slot_token[i] = -1;
#pragma unroll
  for (int e = 0; e < 8; ++e) hist[t][e] = 0;
  const int base = t * 64;
  for (int i = 0; i < 64; ++i) hist[t][g_tope[base + i]]++;
  __syncthreads();
  if (t < 8) {
    int run = 0;
    for (int j = 0; j < 256; ++j) { int v = hist[j][t]; hist[j][t] = run; run += v; }
    g_cnt_all[t]  = run;
    g_cnt_used[t] = run < CAP_ ? run : CAP_;
  }
  __syncthreads();
  for (int i = 0; i < 64; ++i) {
    int item = base + i;
    int e = g_tope[item];
    int pos = hist[t][e]++;
    if (pos < CAP_) {
      g_slotof[item] = pos;
      g_slot_token[e * CAP_ + pos] = item & (N_ - 1);
      g_slot_gate [e * CAP_ + pos] = g_gatew[item];
    } else {
      g_slotof[item] = -1;
    }
  }
}

// ---------------- dispatch: fill expert buffers (gate * raw x), bf16; zeros for empty slots ----------------
__global__ __launch_bounds__(256) void k_dispatch(const float* __restrict__ x) {
  const int e = blockIdx.y;
  const int c = blockIdx.x * 4 + (threadIdx.x >> 6);
  const int lane = threadIdx.x & 63;
  const int tok = g_slot_token[e * CAP_ + c];
  unsigned short* dst = g_A + ((size_t)e * CAP_ + c) * H_;
  if (tok < 0) {
    s16x8 z = (s16x8)0;
#pragma unroll
    for (int i = 0; i < 4; ++i) *(s16x8*)(dst + i * 512 + lane * 8) = z;
  } else {
    const float gate = g_slot_gate[e * CAP_ + c];
    const float* xr = x + (size_t)tok * H_;
#pragma unroll
    for (int i = 0; i < 4; ++i) {
      int idx = i * 512 + lane * 8;
      float4 a = *(const float4*)(xr + idx);
      float4 b = *(const float4*)(xr + idx + 4);
      s16x8 v;
      v[0] = (short)f2bfu(gate * a.x); v[1] = (short)f2bfu(gate * a.y);
      v[2] = (short)f2bfu(gate * a.z); v[3] = (short)f2bfu(gate * a.w);
      v[4] = (short)f2bfu(gate * b.x); v[5] = (short)f2bfu(gate * b.y);
      v[6] = (short)f2bfu(gate * b.z); v[7] = (short)f2bfu(gate * b.w);
      *(s16x8*)(dst + idx) = v;
    }
  }
}

// ---------------- fused GEMM01: h = silu(A@w1) * (A@w3), 128x128 tile, BK=32, 4 waves ----------------
// A staged once, two B streams, dual accumulators. Writes bf16 h to g_S1.
__global__ __launch_bounds__(256, 2) void k_gemm01() {
  const int e = blockIdx.z;
  const int m0 = blockIdx.y * 128;
  if (m0 >= g_cnt_used[e]) return;
  const int n0 = blockIdx.x * 128;
  __shared__ __align__(16) unsigned short As [128 * 32];
  __shared__ __align__(16) unsigned short B1s[128 * 32];
  __shared__ __align__(16) unsigned short B3s[128 * 32];
  const int t = threadIdx.x, wave = t >> 6, lane = t & 63;
  const int wr = wave >> 1, wc = wave & 1;
  const int fq = lane >> 4, fr = lane & 15;
  const unsigned short* ga  = g_A   + (size_t)e * CAP_ * H_ + (size_t)(m0 + (t >> 2)) * H_ + (t & 3) * 8;
  const unsigned short* gb1 = g_w1t + (size_t)e * F_   * H_ + (size_t)(n0 + (t >> 2)) * H_ + (t & 3) * 8;
  const unsigned short* gb3 = g_w3t + (size_t)e * F_   * H_ + (size_t)(n0 + (t >> 2)) * H_ + (t & 3) * 8;
  unsigned short* lwa  = As  + wave * 512;   // wave-uniform LDS dest (1024B/wave)
  unsigned short* lwb1 = B1s + wave * 512;
  unsigned short* lwb3 = B3s + wave * 512;
  const unsigned short* pa  = As  + (size_t)(wr * 64 + fr) * 32 + fq * 8;
  const unsigned short* pb1 = B1s + (size_t)(wc * 64 + fr) * 32 + fq * 8;
  const unsigned short* pb3 = B3s + (size_t)(wc * 64 + fr) * 32 + fq * 8;
  f32x4 acc1[4][4] = {};
  f32x4 acc3[4][4] = {};
  for (int kt = 0; kt < (H_ >> 5); ++kt) {
    const int ko = kt * 32;
    gload16(ga  + ko, lwa);
    gload16(ga  + ko + (size_t)64 * H_, lwa  + 2048);
    gload16(gb1 + ko, lwb1);
    gload16(gb1 + ko + (size_t)64 * H_, lwb1 + 2048);
    gload16(gb3 + ko, lwb3);
    gload16(gb3 + ko + (size_t)64 * H_, lwb3 + 2048);
    __syncthreads();   // compiler drains vmcnt before s_barrier
    s16x8 af[4], b1f[4], b3f[4];
#pragma unroll
    for (int m = 0; m < 4; ++m) af[m] = *(const s16x8*)(pa + m * 512);
#pragma unroll
    for (int nn = 0; nn < 4; ++nn) b1f[nn] = *(const s16x8*)(pb1 + nn * 512);
#pragma unroll
    for (int nn = 0; nn < 4; ++nn) b3f[nn] = *(const s16x8*)(pb3 + nn * 512);
#pragma unroll
    for (int m = 0; m < 4; ++m)
#pragma unroll
      for (int nn = 0; nn < 4; ++nn) {
        acc1[m][nn] = __builtin_amdgcn_mfma_f32_16x16x32_bf16(af[m], b1f[nn], acc1[m][nn], 0, 0, 0);
        acc3[m][nn] = __builtin_amdgcn_mfma_f32_16x16x32_bf16(af[m], b3f[nn], acc3[m][nn], 0, 0, 0);
      }
    __syncthreads();
  }
#pragma unroll
  for (int m = 0; m < 4; ++m) {
    const int grow_base = m0 + wr * 64 + m * 16 + fq * 4;
#pragma unroll
    for (int nn = 0; nn < 4; ++nn) {
      const int gcol = n0 + wc * 64 + nn * 16 + fr;
#pragma unroll
      for (int j = 0; j < 4; ++j) {
        const int grow = grow_base + j;
        const float s1 = acc1[m][nn][j];
        const float s3 = acc3[m][nn][j];
        const float hv = (s1 / (1.f + expf(-s1))) * s3;   // silu(s1) * s3
        g_S1[(size_t)e * CAP_ * F_ + (size_t)grow * F_ + gcol] = f2bfu(hv);
      }
    }
  }
}

// ---------------- GEMM2: eout = h @ w2t, 128x128 tile, BK=32, 4 waves ----------------
__global__ __launch_bounds__(256) void k_gemm2() {
  const int e = blockIdx.z;
  const int m0 = blockIdx.y * 128;
  if (m0 >= g_cnt_used[e]) return;
  const int n0 = blockIdx.x * 128;
  __shared__ __align__(16) unsigned short As[128 * 32];
  __shared__ __align__(16) unsigned short Bs[128 * 32];
  const int t = threadIdx.x, wave = t >> 6, lane = t & 63;
  const int wr = wave >> 1, wc = wave & 1;
  const int fq = lane >> 4, fr = lane & 15;
  const unsigned short* ga = g_S1  + (size_t)e * CAP_ * F_ + (size_t)(m0 + (t >> 2)) * F_ + (t & 3) * 8;
  const unsigned short* gb = g_w2t + (size_t)e * H_   * F_ + (size_t)(n0 + (t >> 2)) * F_ + (t & 3) * 8;
  unsigned short* lwa = As + wave * 512;
  unsigned short* lwb = Bs + wave * 512;
  const unsigned short* pa = As + (size_t)(wr * 64 + fr) * 32 + fq * 8;
  const unsigned short* pb = Bs + (size_t)(wc * 64 + fr) * 32 + fq * 8;
  f32x4 acc[4][4] = {};
  for (int kt = 0; kt < (F_ >> 5); ++kt) {
    const int ko = kt * 32;
    gload16(ga + ko, lwa);
    gload16(ga + ko + (size_t)64 * F_, lwa + 2048);
    gload16(gb + ko, lwb);
    gload16(gb + ko + (size_t)64 * F_, lwb + 2048);
    __syncthreads();
    s16x8 af[4], bfr[4];
#pragma unroll
    for (int m = 0; m < 4; ++m) af[m] = *(const s16x8*)(pa + m * 512);
#pragma unroll
    for (int nn = 0; nn < 4; ++nn) bfr[nn] = *(const s16x8*)(pb + nn * 512);
#pragma unroll
    for (int m = 0; m < 4; ++m)
#pragma unroll
      for (int nn = 0; nn < 4; ++nn)
        acc[m][nn] = __builtin_amdgcn_mfma_f32_16x16x32_bf16(af[m], bfr[nn], acc[m][nn], 0, 0, 0);
    __syncthreads();
  }
#pragma unroll
  for (int m = 0; m < 4; ++m) {
    const int grow_base = m0 + wr * 64 + m * 16 + fq * 4;
#pragma unroll
    for (int nn = 0; nn < 4; ++nn) {
      const int gcol = n0 + wc * 64 + nn * 16 + fr;
#pragma unroll
      for (int j = 0; j < 4; ++j)
        g_eout[(size_t)e * CAP_ * H_ + (size_t)(grow_base + j) * H_ + gcol] = acc[m][nn][j];
    }
  }
}

// ---------------- combine: out[n] = sum_k assigned ? eout[e_k][slot_k] : 0 ; + aux loss ----------------
__global__ __launch_bounds__(256) void k_combine(float* __restrict__ out) {
  const int n = blockIdx.x, t = threadIdx.x;
  if (n == 0 && t == 0) {
    float a = 0.f;
#pragma unroll
    for (int e = 0; e < E_; ++e)
      a += (g_me[e] / (float)N_) * ((float)g_cnt_all[e] / (float)(2 * N_));
    out[(size_t)N_ * H_] = 0.01f * (float)E_ * a;
  }
  const int e0 = g_tope[n],       e1 = g_tope[N_ + n];
  const int s0 = g_slotof[n],     s1 = g_slotof[N_ + n];
  const bool b0 = s0 >= 0, b1 = s1 >= 0;
  const float* p0 = g_eout + ((size_t)e0 * CAP_ + (b0 ? s0 : 0)) * H_;
  const float* p1 = g_eout + ((size_t)e1 * CAP_ + (b1 ? s1 : 0)) * H_;
#pragma unroll
  for (int i = 0; i < 2; ++i) {
    const int idx = i * 1024 + t * 4;
    float4 v = make_float4(0.f, 0.f, 0.f, 0.f);
    if (b0) { float4 a = *(const float4*)(p0 + idx); v.x += a.x; v.y += a.y; v.z += a.z; v.w += a.w; }
    if (b1) { float4 a = *(const float4*)(p1 + idx); v.x += a.x; v.y += a.y; v.z += a.z; v.w += a.w; }
    *(float4*)(out + (size_t)n * H_ + idx) = v;
  }
}

// ---------------- launch ----------------
extern "C" void kernel_launch(void* const* d_in, const int* in_sizes, int n_in,
                              void* d_out, int out_size, void* d_ws, size_t ws_size,
                              hipStream_t stream) {
  const float* x     = (const float*)d_in[0];
  // d_in[1] positions: unused by the reference math
  const float* ph    = (const float*)d_in[2];
  const float* rmsw  = (const float*)d_in[3];
  const float* Wg    = (const float*)d_in[4];
  const float* Wctx  = (const float*)d_in[5];
  const float* Wctx2 = (const float*)d_in[6];
  const float* w1    = (const float*)d_in[7];
  const float* w2    = (const float*)d_in[8];
  const float* w3    = (const float*)d_in[9];
  float* out = (float*)d_out;

  // weight convert + transpose to bf16 B^T layouts
  k_convT<0><<<dim3(F_ / 64, H_ / 64, E_), 256, 0, stream>>>(w1);
  k_convT<1><<<dim3(F_ / 64, H_ / 64, E_), 256, 0, stream>>>(w3);
  k_convT<2><<<dim3(H_ / 64, F_ / 64, E_), 256, 0, stream>>>(w2);
  // routing
  k_ctx<<<1, 256, 0, stream>>>(ph, Wctx, Wctx2);
  k_router<<<N_ / 4, 256, 0, stream>>>(x, rmsw, Wg);
  k_scan<<<1, 256, 0, stream>>>();
  k_dispatch<<<dim3(CAP_ / 4, E_), 256, 0, stream>>>(x);
  // expert FFN (grouped over blockIdx.z)
  k_gemm01<<<dim3(F_ / 128, CAP_ / 128, E_), 256, 0, stream>>>();
  k_gemm2 <<<dim3(H_ / 128, CAP_ / 128, E_), 256, 0, stream>>>();
  // combine (+aux)
  k_combine<<<N_, 256, 0, stream>>>(out);
}